// Round 4
// baseline (4552.604 us; speedup 1.0000x reference)
//
#include <hip/hip_runtime.h>
#include <cstdint>

// ---- problem dims ----
#define Hdim 512
#define Bdim 128
#define Tdim 512
#define FUT  32
#define TT   (Tdim + FUT)   // 544
#define RD   8              // h ring depth (parity & 7)
#define FSTR 32             // flag stride in u32 (one flag per 128-B line)
#define CAPIT (1 << 22)     // spin-loop safety cap (fail fast instead of hang)

typedef _Float16 f16;
typedef f16      half8  __attribute__((ext_vector_type(8)));
typedef float    f32x4  __attribute__((ext_vector_type(4)));
typedef unsigned long long ull;

// ---- ws layout (float offsets) ----  (layout kept from R3; local rings unused)
#define AW1_OFF  0
#define AW2R_OFF (AW1_OFF + 1048576)     // W_hh2 packed
#define AW2I_OFF (AW2R_OFF + 1048576)    // W_ih2 packed
#define B1P_OFF  (AW2I_OFF + 1048576)
#define B2P_OFF  (B1P_OFF + 2048)
#define WX1_OFF  (B2P_OFF + 2048)
#define XT_OFF   (WX1_OFF + 2048)        // [512 t][128 b] f32
#define H1G_OFF  (XT_OFF + 65536)        // h1 ring: 8 par x 2 spl x 65536 f16
#define H2G_OFF  (H1G_OFF + 524288)      // h2 ring
#define H1L0_OFF (H2G_OFF + 524288)      // (unused this round)
#define PB_OFF   (H1L0_OFF + 1048576)    // P ring: 2 par x 2 g x 32 blk x 16 x 64 x f32x4
#define ARR_OFF  (PB_OFF + 524288)       // flags + per-XCD counters (8192 u32 = 256 lines)
#define WS_FLOATS (ARR_OFF + 8192)

// flag lines: f1 @ g*32+i (0..63), fP @ 64+g*32+i, f2 @ 128+g*32+i,
// fog @ 192+g*4+q, XCD counters @ 200+xcd.  All agent-scope atomics (R0-proven).
#define F1Gp(g,i)  (flg + ((g)*32 + (i)) * FSTR)
#define FPp(g,i)   (flg + (64 + (g)*32 + (i)) * FSTR)
#define F2Gp(g,i)  (flg + (128 + (g)*32 + (i)) * FSTR)
#define FOGp(g,q)  (flg + (192 + (g)*4 + (q)) * FSTR)

__device__ __forceinline__ float sigm(float v) { return 1.0f / (1.0f + __expf(-v)); }
__device__ __forceinline__ float tanh_fast(float v) {
    v = fminf(fmaxf(v, -20.0f), 20.0f);
    float e = __expf(2.0f * v);
    return (e - 1.0f) / (e + 1.0f);
}

// ---- R0-proven coherent primitives: relaxed agent-scope atomics only ----
__device__ __forceinline__ unsigned cohloadu(const unsigned* p) {
    return __hip_atomic_load(p, __ATOMIC_RELAXED, __HIP_MEMORY_SCOPE_AGENT);
}
__device__ __forceinline__ void cohstoreu(unsigned* p, unsigned v) {
    __hip_atomic_store(p, v, __ATOMIC_RELAXED, __HIP_MEMORY_SCOPE_AGENT);
}
__device__ __forceinline__ ull cohload64(const ull* p) {
    return __hip_atomic_load(p, __ATOMIC_RELAXED, __HIP_MEMORY_SCOPE_AGENT);
}
__device__ __forceinline__ void cohstore64(ull* p, ull v) {
    __hip_atomic_store(p, v, __ATOMIC_RELAXED, __HIP_MEMORY_SCOPE_AGENT);
}
union HB  { ull u[2]; half8 h; };
union HB4 { ull u[2]; f32x4 f; };
__device__ __forceinline__ half8 fragload(const half8* p) {
    const ull* q = (const ull*)p;
    HB t; t.u[0] = cohload64(q); t.u[1] = cohload64(q + 1);
    return t.h;
}

// ---------- prep ----------
__global__ void lstm_prep(const float* __restrict__ x,
                          const float* __restrict__ W_ih1, const float* __restrict__ W_hh1,
                          const float* __restrict__ b_ih1, const float* __restrict__ b_hh1,
                          const float* __restrict__ W_ih2, const float* __restrict__ W_hh2,
                          const float* __restrict__ b_ih2, const float* __restrict__ b_hh2,
                          float* __restrict__ ws, float* __restrict__ out) {
    int i = blockIdx.x * blockDim.x + threadIdx.x;
    f16* aw1  = (f16*)(ws + AW1_OFF);
    f16* aw2r = (f16*)(ws + AW2R_OFF);
    f16* aw2i = (f16*)(ws + AW2I_OFF);

    if (i < 131072) {                         // AW1 <- W_hh1 (proven packing)
        int mt = i >> 10, rest = i & 1023, ks = rest >> 6, lane = rest & 63;
        int m = mt * 16 + (lane & 15);
        int u = m >> 2, g = m & 3;
        int kbase = ks * 32 + (lane >> 4) * 8;
        size_t ohi = ((((size_t)mt * 16 + ks) * 2 + 0) * 64 + lane) * 8;
        size_t olo = ((((size_t)mt * 16 + ks) * 2 + 1) * 64 + lane) * 8;
        #pragma unroll
        for (int j = 0; j < 8; ++j) {
            float wv = W_hh1[(size_t)(g * Hdim + u) * Hdim + kbase + j];
            f16 hi = (f16)wv;
            f16 lo = (f16)(wv - (float)hi);
            aw1[ohi + j] = hi; aw1[olo + j] = lo;
        }
    }
    if (i >= 131072 && i < 262144) {          // AW2R <- W_hh2 (same format)
        int i2 = i - 131072;
        int mt = i2 >> 10, rest = i2 & 1023, ks = rest >> 6, lane = rest & 63;
        int m = mt * 16 + (lane & 15);
        int u = m >> 2, g = m & 3;
        int kbase = ks * 32 + (lane >> 4) * 8;
        size_t ohi = ((((size_t)mt * 16 + ks) * 2 + 0) * 64 + lane) * 8;
        size_t olo = ((((size_t)mt * 16 + ks) * 2 + 1) * 64 + lane) * 8;
        #pragma unroll
        for (int j = 0; j < 8; ++j) {
            float wv = W_hh2[(size_t)(g * Hdim + u) * Hdim + kbase + j];
            f16 hi = (f16)wv;
            f16 lo = (f16)(wv - (float)hi);
            aw2r[ohi + j] = hi; aw2r[olo + j] = lo;
        }
    }
    if (i >= 262144 && i < 393216) {          // AW2I <- W_ih2 (same format)
        int i2 = i - 262144;
        int mt = i2 >> 10, rest = i2 & 1023, ks = rest >> 6, lane = rest & 63;
        int m = mt * 16 + (lane & 15);
        int u = m >> 2, g = m & 3;
        int kbase = ks * 32 + (lane >> 4) * 8;
        size_t ohi = ((((size_t)mt * 16 + ks) * 2 + 0) * 64 + lane) * 8;
        size_t olo = ((((size_t)mt * 16 + ks) * 2 + 1) * 64 + lane) * 8;
        #pragma unroll
        for (int j = 0; j < 8; ++j) {
            float wv = W_ih2[(size_t)(g * Hdim + u) * Hdim + kbase + j];
            f16 hi = (f16)wv;
            f16 lo = (f16)(wv - (float)hi);
            aw2i[ohi + j] = hi; aw2i[olo + j] = lo;
        }
    }
    if (i < Hdim) {
        float4 bb1 = { b_ih1[i] + b_hh1[i],               b_ih1[Hdim+i] + b_hh1[Hdim+i],
                       b_ih1[2*Hdim+i] + b_hh1[2*Hdim+i], b_ih1[3*Hdim+i] + b_hh1[3*Hdim+i] };
        float4 bb2 = { b_ih2[i] + b_hh2[i],               b_ih2[Hdim+i] + b_hh2[Hdim+i],
                       b_ih2[2*Hdim+i] + b_hh2[2*Hdim+i], b_ih2[3*Hdim+i] + b_hh2[3*Hdim+i] };
        float4 wx  = { W_ih1[i], W_ih1[Hdim+i], W_ih1[2*Hdim+i], W_ih1[3*Hdim+i] };
        ((float4*)(ws + B1P_OFF))[i] = bb1;
        ((float4*)(ws + B2P_OFF))[i] = bb2;
        ((float4*)(ws + WX1_OFF))[i] = wx;
    }
    if (i < Tdim * Bdim) {
        int t = i >> 7, b = i & 127;
        ws[XT_OFF + i] = x[b * Tdim + t];
    }
    if (i < 262144) {                          // zero h1/h2 rings (+ unused region)
        ((ull*)(ws + H1G_OFF))[i] = 0;
        ((ull*)(ws + H2G_OFF))[i] = 0;
        ((ull*)(ws + H1L0_OFF))[i] = 0;
        ((ull*)(ws + PB_OFF))[i & 262143] = 0;
    }
    if (i < 8192) ((unsigned*)(ws + ARR_OFF))[i] = 0u;
    if (i < Bdim * TT) out[i] = 0.f;           // out is accumulated via atomicAdd
}

// ---------- persistent main kernel: XCD-partitioned 4-stage pipeline ----------
// Roles by measured XCC_ID (placement-safe), ALL data via agent-scope atomics:
//   XCD0/1: L1 group 0/1 (32 blk, 16 units, K=512 h1 recurrence)
//   XCD2/3: L2 group 0/1 (32 blk, 16 units, K=512 W_hh2 h2 recurrence + P add)
//   XCD4/5: L2in group 0/1 (32 blk: P(s) = W_ih2 . h1(s) + b2; slack stage)
//   XCD6:   8 out blocks (4 per group, ks-quartered, atomicAdd into out)
__global__ __launch_bounds__(256, 1) void lstm_main(float* ws,
                                                    const float* __restrict__ Wout,
                                                    const float* __restrict__ bout,
                                                    float* __restrict__ out) {
    const int tid  = threadIdx.x;
    const int w    = tid >> 6;
    const int lane = tid & 63;
    const int quad = lane >> 4;
    const int col  = lane & 15;

    __shared__ f16   awlds[65536];       // 128 KB weight A-fragments (forces 1 blk/CU)
    __shared__ float wout_lds[Hdim];
    __shared__ float psum[4][64];
    __shared__ float xflds[64];
    __shared__ float qpart[4][64];
    __shared__ __align__(16) ull hstg[512];
    __shared__ int sXcd, sOrd, badf;

    unsigned* flg = (unsigned*)(ws + ARR_OFF);
    unsigned short* stg = (unsigned short*)hstg;
    const float* xT = ws + XT_OFF;
    const float bout0 = bout[0];

    // ---- runtime XCD discovery + per-XCD ordinal ----
    if (tid == 0) {
        badf = 0;
        unsigned xcc;
        asm volatile("s_getreg_b32 %0, hwreg(HW_REG_XCC_ID, 0, 32)" : "=s"(xcc));
        xcc &= 0xF;
        sXcd = (int)xcc;
        sOrd = (int)atomicAdd(flg + (200 + xcc) * FSTR, 1u);
    }
    __syncthreads();
    const int xcd = sXcd, ord = sOrd;

    const bool is1   = (xcd < 2);
    const bool is2   = (xcd == 2 || xcd == 3);
    const bool isI   = (xcd == 4 || xcd == 5);
    const bool isout = (xcd == 6) && (ord < 8);
    const bool active = ((is1 || is2 || isI) && ord < 32) || isout;
    if (!active) return;

    const int gA  = is1 ? xcd : is2 ? (xcd - 2) : isI ? (xcd - 4) : (ord >> 2);
    const int oq  = isout ? (ord & 3) : 0;
    const int ntw = gA * 4 + w;
    const int ks1 = ord >> 1, qp0 = (ord & 1) * 2;

    // ---- ring fragment planes (half8 index = (nt*16+ks)*64 + lane) ----
    auto h1pf = [&](int par, int spl) {
        return (const half8*)((const unsigned short*)(ws + H1G_OFF) + (size_t)(par*2+spl) * 65536); };
    auto h2pf = [&](int par, int spl) {
        return (const half8*)((const unsigned short*)(ws + H2G_OFF) + (size_t)(par*2+spl) * 65536); };
    auto h1ull = [&](int par, int spl) {
        return (ull*)(ws + H1G_OFF) + (size_t)(par*2+spl) * 16384; };
    auto h2ull = [&](int par, int spl) {
        return (ull*)(ws + H2G_OFF) + (size_t)(par*2+spl) * 16384; };
    auto pidx = [&](int par2, int mt) -> size_t {
        return ((((size_t)par2 * 2 + gA) * 32 + ord) * 16 + (mt * 4 + w)) * 64 + lane;
    };
    ull* Pu = (ull*)(ws + PB_OFF);

    // ---- one-time: weight slice -> LDS ----
    if (is1 || is2 || isI) {
        const half8* s = (const half8*)(ws + (is1 ? AW1_OFF : is2 ? AW2R_OFF : AW2I_OFF))
                       + (size_t)ord * 8192;
        half8* d = (half8*)awlds;
        for (int i = tid; i < 8192; i += 256) d[i] = s[i];
    }
    wout_lds[tid]       = Wout[tid];
    wout_lds[256 + tid] = Wout[256 + tid];
    __syncthreads();

    // ---- shared GEMM core: 16 units x 64 cols, K=512 hi/lo over a ring parity ----
    auto gemm = [&](const half8* fh, const half8* fl, f32x4* acc) {
        half8 rh[16], rl[16];
        #pragma unroll
        for (int ks = 0; ks < 16; ++ks) {
            rh[ks] = fragload(fh + (ntw * 16 + ks) * 64 + lane);
            rl[ks] = fragload(fl + (ntw * 16 + ks) * 64 + lane);
        }
        const half8* aw8 = (const half8*)awlds;
        #pragma unroll
        for (int ks = 0; ks < 16; ++ks) {
            #pragma unroll
            for (int mt = 0; mt < 4; ++mt) {
                half8 ah = aw8[((mt * 16 + ks) * 2 + 0) * 64 + lane];
                half8 al = aw8[((mt * 16 + ks) * 2 + 1) * 64 + lane];
                acc[mt] = __builtin_amdgcn_mfma_f32_16x16x32_f16(ah, rh[ks], acc[mt], 0, 0, 0);
                acc[mt] = __builtin_amdgcn_mfma_f32_16x16x32_f16(al, rh[ks], acc[mt], 0, 0, 0);
                acc[mt] = __builtin_amdgcn_mfma_f32_16x16x32_f16(ah, rl[ks], acc[mt], 0, 0, 0);
            }
        }
    };

    // ---- staging + publish (agent-scope b64 stores, R0-proven path) ----
    auto stage1 = [&](int mt, float hv) {
        f16 hhi = (f16)hv;
        f16 hlo = (f16)(hv - (float)hhi);
        int mq = mt * 4 + quad, qp = mq >> 3, jj = mq & 7;
        int hi = ((w * 2 + qp) * 16 + col) * 8 + jj;
        stg[hi]        = __builtin_bit_cast(unsigned short, hhi);
        stg[1024 + hi] = __builtin_bit_cast(unsigned short, hlo);
    };
    auto publish = [&](int dpar, bool to1) {
        __syncthreads();
        int f = 2 * tid;
        int spl = f >> 8, rmix = f & 255, ntl = rmix >> 6, rr = rmix & 63;
        int qp = rr >> 5, colp = (rr & 31) >> 1;
        size_t e = (((size_t)(gA * 4 + ntl) * 16 + ks1) * 64 + (qp0 + qp) * 16 + colp) * 2;
        ull* base = (to1 ? h1ull(dpar, spl) : h2ull(dpar, spl)) + e;
        cohstore64(base,     hstg[f]);
        cohstore64(base + 1, hstg[f + 1]);
    };

    // ================= LAYER 1 (h1 recurrence) =================
    if (is1) {
        const int bcol = ntw * 16 + col;
        float4 b1v[4], wxv[4]; float c1s[4];
        #pragma unroll
        for (int mt = 0; mt < 4; ++mt) {
            int u = ord * 16 + mt * 4 + quad;
            b1v[mt] = ((const float4*)(ws + B1P_OFF))[u];
            wxv[mt] = ((const float4*)(ws + WX1_OFF))[u];
            c1s[mt] = 0.f;
        }
        unsigned* myF1 = F1Gp(gA, ord);
        unsigned fPc = (tid < 64 && lane >= 32) ? 0u : 0xFFFFFFFFu;  // cached fP

        auto wait_main = [&](unsigned T1, unsigned TP) {
            if (tid < 64 && !badf) {
                int gd = 0;
                for (;;) {
                    unsigned a = (lane < 32) ? cohloadu(F1Gp(gA, lane)) : 0xFFFFFFFFu;
                    if (lane >= 32 && fPc < TP) fPc = cohloadu(FPp(gA, lane - 32));
                    if (__all(a >= T1 && fPc >= TP)) break;
                    if (++gd > CAPIT) { badf = 1; break; }
                    __builtin_amdgcn_s_sleep(4);
                }
            }
            asm volatile("" ::: "memory");
            __syncthreads();
        };
        auto wait_fut = [&](unsigned T) {
            if (tid < 64 && !badf) {
                int gd = 0;
                for (;;) {
                    unsigned a = (lane < 32) ? cohloadu(F1Gp(gA, lane))
                                             : cohloadu(F2Gp(gA, lane - 32));
                    if (__all(a >= T)) break;
                    if (++gd > CAPIT) { badf = 1; break; }
                    __builtin_amdgcn_s_sleep(4);
                }
            }
            asm volatile("" ::: "memory");
            __syncthreads();
        };
        auto post1 = [&](unsigned v) {
            __syncthreads();               // tracked atomic stores drain before barrier
            if (tid == 0) cohstoreu(myF1, v);
        };
        auto l1_step = [&](int spar, int dpar, float xv) {
            f32x4 acc[4] = {};
            gemm(h1pf(spar, 0), h1pf(spar, 1), acc);
            #pragma unroll
            for (int mt = 0; mt < 4; ++mt) {
                f32x4 g = acc[mt];
                float pi = g[0] + b1v[mt].x + wxv[mt].x * xv;
                float pf = g[1] + b1v[mt].y + wxv[mt].y * xv;
                float pg = g[2] + b1v[mt].z + wxv[mt].z * xv;
                float po = g[3] + b1v[mt].w + wxv[mt].w * xv;
                float c = fmaf(sigm(pf), c1s[mt], sigm(pi) * tanh_fast(pg));
                c1s[mt] = c;
                stage1(mt, sigm(po) * tanh_fast(c));
            }
            publish(dpar, true);
        };

        // prologue: h1(0) from x(0), h1(-1)=0
        {
            float xv = xT[bcol];
            #pragma unroll
            for (int mt = 0; mt < 4; ++mt) {
                float pi = b1v[mt].x + wxv[mt].x * xv;
                float pg = b1v[mt].z + wxv[mt].z * xv;
                float po = b1v[mt].w + wxv[mt].w * xv;
                float c = sigm(pi) * tanh_fast(pg);
                c1s[mt] = c;
                stage1(mt, sigm(po) * tanh_fast(c));
            }
            publish(0, true);
            post1(1u);
        }
        // main: step t computes h1(t+1); fP backpressure protects h1 ring vs L2in
        for (int t = 0; t <= Tdim - 2; ++t) {
            wait_main((unsigned)(t + 1), (t >= 7) ? (unsigned)(t - 6) : 0u);
            l1_step(t & 7, (t + 1) & 7, xT[(t + 1) * Bdim + bcol]);
            post1((unsigned)(t + 2));
        }
        // future: compute O(t-1) from h2 ring, feed back as x
        for (int t = Tdim; t < TT; ++t) {
            wait_fut((unsigned)t);
            {
                int bl = tid & 63, kh = tid >> 6;
                int nt2 = gA * 4 + (bl >> 4), nl = bl & 15;
                const half8* ph = h2pf((t - 1) & 7, 0);
                const half8* pl = h2pf((t - 1) & 7, 1);
                float a = 0.f;
                #pragma unroll
                for (int kk = 0; kk < 4; ++kk) {
                    int ks = kh * 4 + kk;
                    #pragma unroll
                    for (int qd = 0; qd < 4; ++qd) {
                        half8 vh = fragload(ph + (nt2 * 16 + ks) * 64 + qd * 16 + nl);
                        half8 vl = fragload(pl + (nt2 * 16 + ks) * 64 + qd * 16 + nl);
                        int ub = ks * 32 + qd * 8;
                        #pragma unroll
                        for (int j = 0; j < 8; ++j)
                            a = fmaf((float)vh[j] + (float)vl[j], wout_lds[ub + j], a);
                    }
                }
                psum[kh][bl] = a;
                __syncthreads();
                if (tid < 64)
                    xflds[tid] = psum[0][tid] + psum[1][tid] + psum[2][tid]
                               + psum[3][tid] + bout0;
                __syncthreads();
            }
            l1_step((t - 1) & 7, t & 7, xflds[bcol & 63]);
            post1((unsigned)(t + 1));
        }
    }
    // ================= LAYER 2 recurrent half =================
    else if (is2) {
        float c2s[4] = {0.f, 0.f, 0.f, 0.f};
        unsigned* myF2 = F2Gp(gA, ord);
        unsigned* myFP = FPp(gA, ord);
        unsigned fPc2 = (tid < 64 && lane == 0) ? 0u : 0xFFFFFFFFu;
        unsigned fogc = (tid < 64 && lane >= 32 && lane < 36) ? 0u : 0xFFFFFFFFu;

        auto waitP = [&](unsigned T) {
            if (tid < 64 && !badf) {
                int gd = 0;
                for (;;) {
                    if (lane == 0 && fPc2 < T) fPc2 = cohloadu(myFP);
                    if (__all(fPc2 >= T)) break;
                    if (++gd > CAPIT) { badf = 1; break; }
                    __builtin_amdgcn_s_sleep(4);
                }
            }
            asm volatile("" ::: "memory");
            __syncthreads();
        };
        auto waitB = [&](unsigned T2, unsigned To) {
            if (tid < 64 && !badf) {
                int gd = 0;
                for (;;) {
                    unsigned a = (lane < 32) ? cohloadu(F2Gp(gA, lane)) : 0xFFFFFFFFu;
                    if (lane >= 32 && lane < 36 && fogc < To) fogc = cohloadu(FOGp(gA, lane - 32));
                    if (__all(a >= T2 && fogc >= To)) break;
                    if (++gd > CAPIT) { badf = 1; break; }
                    __builtin_amdgcn_s_sleep(4);
                }
            }
            asm volatile("" ::: "memory");
            __syncthreads();
        };

        for (int s = 0; s < TT; ++s) {
            int cpar = s & 7, ppar = (s - 1) & 7;
            waitP((unsigned)(s + 1));                 // P(s) ready (usually pre-satisfied)
            HB4 praw[4];
            #pragma unroll
            for (int mt = 0; mt < 4; ++mt) {          // prefetch P(s); tracked loads
                const ull* q = Pu + pidx(s & 1, mt) * 2;
                praw[mt].u[0] = cohload64(q);
                praw[mt].u[1] = cohload64(q + 1);
            }
            waitB((unsigned)s, (s >= 8) ? (unsigned)(s - 7) : 0u);

            f32x4 acc[4] = {};
            if (s > 0) gemm(h2pf(ppar, 0), h2pf(ppar, 1), acc);  // h2(-1)=0
            #pragma unroll
            for (int mt = 0; mt < 4; ++mt) {
                f32x4 g = acc[mt];
                f32x4 p = praw[mt].f;
                float pi = g[0] + p[0], pf = g[1] + p[1];
                float pg = g[2] + p[2], po = g[3] + p[3];
                float c = fmaf(sigm(pf), c2s[mt], sigm(pi) * tanh_fast(pg));
                c2s[mt] = c;
                stage1(mt, sigm(po) * tanh_fast(c));
            }
            publish(cpar, false);
            __syncthreads();
            if (tid == 0) cohstoreu(myF2, (unsigned)(s + 1));
        }
    }
    // ================= L2-input stage: P(s) = W_ih2 . h1(s) + b2 =================
    else if (isI) {
        float4 b2v[4];
        #pragma unroll
        for (int mt = 0; mt < 4; ++mt)
            b2v[mt] = ((const float4*)(ws + B2P_OFF))[ord * 16 + mt * 4 + quad];
        unsigned* myFP = FPp(gA, ord);
        unsigned f1c = (tid < 64 && lane < 32) ? 0u : 0xFFFFFFFFu;
        unsigned f2c = (tid < 64 && lane >= 32) ? 0u : 0xFFFFFFFFu;

        auto waitI = [&](unsigned T1, unsigned T2) {
            if (tid < 64 && !badf) {
                int gd = 0;
                for (;;) {
                    if (lane < 32 && f1c < T1) f1c = cohloadu(F1Gp(gA, lane));
                    if (lane >= 32 && f2c < T2) f2c = cohloadu(F2Gp(gA, lane - 32));
                    if (__all(f1c >= T1 && f2c >= T2)) break;
                    if (++gd > CAPIT) { badf = 1; break; }
                    __builtin_amdgcn_s_sleep(4);
                }
            }
            asm volatile("" ::: "memory");
            __syncthreads();
        };

        for (int s = 0; s < TT; ++s) {
            // f1 >= s+1: h1(s) ready; f2 >= s-1: P ring (depth 2) slot free
            waitI((unsigned)(s + 1), (s >= 2) ? (unsigned)(s - 1) : 0u);
            f32x4 acc[4] = {};
            gemm(h1pf(s & 7, 0), h1pf(s & 7, 1), acc);
            #pragma unroll
            for (int mt = 0; mt < 4; ++mt) {
                HB4 p;
                p.f = acc[mt];
                p.f[0] += b2v[mt].x; p.f[1] += b2v[mt].y;
                p.f[2] += b2v[mt].z; p.f[3] += b2v[mt].w;
                ull* q = Pu + pidx(s & 1, mt) * 2;
                cohstore64(q,     p.u[0]);
                cohstore64(q + 1, p.u[1]);
            }
            __syncthreads();
            if (tid == 0) cohstoreu(myFP, (unsigned)(s + 1));
        }
    }
    // ================= OUT blocks (4 per group, ks-quartered, atomicAdd) =================
    else {
        int b = gA * 64 + lane;
        int nt = b >> 4, nl = b & 15;
        int ks = oq * 4 + w;                 // one ks per wave
        unsigned* myFO = FOGp(gA, oq);

        auto waitO = [&](unsigned T) {
            if (tid < 64 && !badf) {
                int gd = 0;
                for (;;) {
                    unsigned a = (lane < 32) ? cohloadu(F2Gp(gA, lane)) : 0xFFFFFFFFu;
                    if (__all(a >= T)) break;
                    if (++gd > CAPIT) { badf = 1; break; }
                    __builtin_amdgcn_s_sleep(4);
                }
            }
            asm volatile("" ::: "memory");
            __syncthreads();
        };

        for (int s = 0; s < TT; ++s) {
            waitO((unsigned)(s + 1));
            const half8* ph = h2pf(s & 7, 0);
            const half8* pl = h2pf(s & 7, 1);
            float a = 0.f;
            #pragma unroll
            for (int qd = 0; qd < 4; ++qd) {
                half8 vh = fragload(ph + (nt * 16 + ks) * 64 + qd * 16 + nl);
                half8 vl = fragload(pl + (nt * 16 + ks) * 64 + qd * 16 + nl);
                int ub = ks * 32 + qd * 8;
                #pragma unroll
                for (int j = 0; j < 8; ++j)
                    a = fmaf((float)vh[j] + (float)vl[j], wout_lds[ub + j], a);
            }
            qpart[w][lane] = a;
            __syncthreads();
            if (w == 0) {
                float v = qpart[0][lane] + qpart[1][lane] + qpart[2][lane] + qpart[3][lane];
                if (oq == 0) v += bout0;
                atomicAdd(&out[(size_t)b * TT + s], v);
            }
            __syncthreads();
            if (tid == 0) cohstoreu(myFO, (unsigned)(s + 1));
        }
    }
}

extern "C" void kernel_launch(void* const* d_in, const int* in_sizes, int n_in,
                              void* d_out, int out_size, void* d_ws, size_t ws_size,
                              hipStream_t stream) {
    const float* x     = (const float*)d_in[0];
    const float* W_ih1 = (const float*)d_in[1];
    const float* W_hh1 = (const float*)d_in[2];
    const float* b_ih1 = (const float*)d_in[3];
    const float* b_hh1 = (const float*)d_in[4];
    const float* W_ih2 = (const float*)d_in[5];
    const float* W_hh2 = (const float*)d_in[6];
    const float* b_ih2 = (const float*)d_in[7];
    const float* b_hh2 = (const float*)d_in[8];
    const float* W_out = (const float*)d_in[9];
    const float* b_out = (const float*)d_in[10];
    float* ws  = (float*)d_ws;
    float* out = (float*)d_out;

    hipLaunchKernelGGL(lstm_prep, dim3(1536), dim3(256), 0, stream,
                       x, W_ih1, W_hh1, b_ih1, b_hh1, W_ih2, W_hh2, b_ih2, b_hh2, ws, out);
    hipLaunchKernelGGL(lstm_main, dim3(256), dim3(256), 0, stream,
                       ws, W_out, b_out, out);
}